// Round 1
// baseline (615.853 us; speedup 1.0000x reference)
//
#include <hip/hip_runtime.h>

#define E_TOTAL 200000
#define IND 256
#define HIDD 512
#define OUTD 5

typedef __attribute__((ext_vector_type(4))) float f32x4;
typedef __attribute__((ext_vector_type(8))) __bf16 bf16x8;

static __device__ __forceinline__ unsigned short f2bf(float f) {
  union { float f; unsigned u; } v; v.f = f;
  unsigned u = v.u;
  unsigned r = (u + 0x7FFFu + ((u >> 16) & 1u)) >> 16;   // RNE
  return (unsigned short)r;
}

// ---------------------------------------------------------------------------
// Pack W0,W1 [512x512] and W2 [512x5] (fp32, row-major K x N) into bf16 MFMA
// B-fragment order so the main kernel's weight loads are contiguous 1KB/wave.
// Fragment layout for mfma_f32_16x16x32_bf16 B-operand:
//   lane l holds B[k0*32 + (l>>4)*8 + j][nt*16 + (l&15)], j=0..7
// Packed elem index: (((nt*16 + k0)*64 + lane)*8 + j
// ws layout (ushort elems): [0,262144) W0p | [262144,524288) W1p | [524288,532480) W2p
// ---------------------------------------------------------------------------
__global__ __launch_bounds__(256) void pack_weights(
    const float* __restrict__ W0, const float* __restrict__ W1,
    const float* __restrict__ W2, unsigned short* __restrict__ wp) {
  int tid = blockIdx.x * 256 + threadIdx.x;
  if (tid < 2 * 262144) {
    int sel = tid >> 18;
    int t = tid & 262143;
    int n = t & 511, k = t >> 9;            // coalesced read along n
    const float* W = sel ? W1 : W0;
    float val = W[k * 512 + n];
    int nt = n >> 4, k0 = k >> 5;
    int lane = (((k >> 3) & 3) << 4) | (n & 15);
    int j = k & 7;
    int off = (((nt * 16 + k0) * 64 + lane) << 3) | j;
    wp[sel * 262144 + off] = f2bf(val);
  } else {
    int t2 = tid - 524288;
    if (t2 < 8192) {                         // W2 padded N=5 -> 16
      int j = t2 & 7, lane = (t2 >> 3) & 63, k0 = t2 >> 9;
      int k = k0 * 32 + ((lane >> 4) << 3) + j;
      int n = lane & 15;
      float val = (n < OUTD) ? W2[k * OUTD + n] : 0.0f;
      wp[524288 + t2] = f2bf(val);
    }
  }
}

// ---------------------------------------------------------------------------
// Fused edge-MLP. One block = 64 edges. LDS: single [64][512] bf16 activation
// buffer, XOR-swizzled (byte ^= (row&7)<<4 within each row) so ds_read_b128
// A-fragment reads (16 lanes = 16 consecutive rows) are bank-conflict-free.
// Layers 0/1: waves partition N (128 cols each), acc[8 ntiles][4 mtiles],
// K-loop 16 steps of 16x16x32 bf16 MFMA. H written back over A (reg-stash +
// 2 barriers). Layer 2: wave w owns M-tile w, single padded n-tile; pair-mean
// is in-lane (C frag rows (q*4..q*4+3) contain both pair members).
// ---------------------------------------------------------------------------
__global__ __launch_bounds__(256, 2) void edge_mlp(
    const float* __restrict__ x, const int* __restrict__ eidx,
    const float* __restrict__ b0, const float* __restrict__ b1,
    const float* __restrict__ b2, const unsigned short* __restrict__ wp,
    float* __restrict__ out) {
  __shared__ uint4 lds4[4096];               // 64 KB
  unsigned char* lds = (unsigned char*)lds4;
  const int tid = threadIdx.x;
  const int lane = tid & 63;
  const int w = tid >> 6;
  const int e0 = blockIdx.x * 64;

  // ---- stage gathered inputs: A[64][512] bf16, cols 0..255 = x[src], 256..511 = x[dst]
  {
    const int r = tid >> 2, p = tid & 3;
    const int e = e0 + r;
    const int node = (p < 2) ? eidx[e] : eidx[E_TOTAL + e];
    const float* xr = x + (size_t)node * IND + (p & 1) * 128;
    const unsigned rowb = (unsigned)r * 1024;
    const unsigned sx = (unsigned)((r & 7) << 4);
    const unsigned colb0 = (unsigned)p * 256;          // p*128 cols * 2B
#pragma unroll
    for (int jj = 0; jj < 16; ++jj) {
      const float4 f0 = *(const float4*)(xr + jj * 8);
      const float4 f1 = *(const float4*)(xr + jj * 8 + 4);
      uint4 pk;
      pk.x = (unsigned)f2bf(f0.x) | ((unsigned)f2bf(f0.y) << 16);
      pk.y = (unsigned)f2bf(f0.z) | ((unsigned)f2bf(f0.w) << 16);
      pk.z = (unsigned)f2bf(f1.x) | ((unsigned)f2bf(f1.y) << 16);
      pk.w = (unsigned)f2bf(f1.z) | ((unsigned)f2bf(f1.w) << 16);
      *(uint4*)(lds + (rowb + (((colb0 + (unsigned)jj * 16)) ^ sx))) = pk;
    }
  }
  __syncthreads();

  const int l15 = lane & 15;
  const int q = lane >> 4;

  // hidden layers
#pragma unroll 1
  for (int L = 0; L < 2; ++L) {
    const unsigned short* wl = wp + L * 262144;
    const float* bias = L ? b1 : b0;

    f32x4 acc[8][4];
#pragma unroll
    for (int nt = 0; nt < 8; ++nt)
#pragma unroll
      for (int m = 0; m < 4; ++m) { acc[nt][m][0]=0.f; acc[nt][m][1]=0.f; acc[nt][m][2]=0.f; acc[nt][m][3]=0.f; }

    for (int k0 = 0; k0 < 16; ++k0) {
      bf16x8 bfr[8];
#pragma unroll
      for (int nt = 0; nt < 8; ++nt) {
        const unsigned short* bp = wl + (size_t)(((w * 8 + nt) * 16 + k0) * 64 + lane) * 8;
        bfr[nt] = *(const bf16x8*)bp;
      }
      bf16x8 a[4];
#pragma unroll
      for (int m = 0; m < 4; ++m) {
        const int row = m * 16 + l15;
        unsigned boff = (unsigned)row * 1024 +
                        (((unsigned)(k0 * 64 + q * 16)) ^ ((unsigned)(row & 7) << 4));
        a[m] = *(const bf16x8*)(lds + boff);
      }
#pragma unroll
      for (int nt = 0; nt < 8; ++nt)
#pragma unroll
        for (int m = 0; m < 4; ++m)
          acc[nt][m] = __builtin_amdgcn_mfma_f32_16x16x32_bf16(a[m], bfr[nt], acc[nt][m], 0, 0, 0);
    }

    // bias + relu + cvt to bf16 stash
    uint2 sv[8][4];
#pragma unroll
    for (int nt = 0; nt < 8; ++nt) {
      const float bv = bias[w * 128 + nt * 16 + l15];
#pragma unroll
      for (int m = 0; m < 4; ++m) {
        float v0 = fmaxf(acc[nt][m][0] + bv, 0.f);
        float v1 = fmaxf(acc[nt][m][1] + bv, 0.f);
        float v2 = fmaxf(acc[nt][m][2] + bv, 0.f);
        float v3 = fmaxf(acc[nt][m][3] + bv, 0.f);
        sv[nt][m].x = (unsigned)f2bf(v0) | ((unsigned)f2bf(v1) << 16);
        sv[nt][m].y = (unsigned)f2bf(v2) | ((unsigned)f2bf(v3) << 16);
      }
    }
    __syncthreads();   // all waves done reading A
#pragma unroll
    for (int nt = 0; nt < 8; ++nt) {
      const unsigned colb = (unsigned)(w * 128 + nt * 16 + l15) * 2;
#pragma unroll
      for (int m = 0; m < 4; ++m) {
        const int r0 = m * 16 + q * 4;
        unsigned short h0 = (unsigned short)(sv[nt][m].x & 0xffff);
        unsigned short h1 = (unsigned short)(sv[nt][m].x >> 16);
        unsigned short h2 = (unsigned short)(sv[nt][m].y & 0xffff);
        unsigned short h3 = (unsigned short)(sv[nt][m].y >> 16);
        *(unsigned short*)(lds + ((unsigned)(r0 + 0) * 1024 + (colb ^ (((r0 + 0) & 7) << 4)))) = h0;
        *(unsigned short*)(lds + ((unsigned)(r0 + 1) * 1024 + (colb ^ (((r0 + 1) & 7) << 4)))) = h1;
        *(unsigned short*)(lds + ((unsigned)(r0 + 2) * 1024 + (colb ^ (((r0 + 2) & 7) << 4)))) = h2;
        *(unsigned short*)(lds + ((unsigned)(r0 + 3) * 1024 + (colb ^ (((r0 + 3) & 7) << 4)))) = h3;
      }
    }
    __syncthreads();
  }

  // output layer: wave w -> M-tile w (rows w*16..w*16+15), single padded n-tile
  f32x4 acc2; acc2[0]=0.f; acc2[1]=0.f; acc2[2]=0.f; acc2[3]=0.f;
  for (int k0 = 0; k0 < 16; ++k0) {
    const int row = w * 16 + l15;
    unsigned boff = (unsigned)row * 1024 +
                    (((unsigned)(k0 * 64 + q * 16)) ^ ((unsigned)(row & 7) << 4));
    bf16x8 a = *(const bf16x8*)(lds + boff);
    const unsigned short* bp = wp + 524288 + (size_t)(k0 * 64 + lane) * 8;
    bf16x8 b = *(const bf16x8*)bp;
    acc2 = __builtin_amdgcn_mfma_f32_16x16x32_bf16(a, b, acc2, 0, 0, 0);
  }
  if (l15 < OUTD) {
    const float bv = b2[l15];
    const int r0 = w * 16 + q * 4;          // block-local edge row (even)
    float v0 = acc2[0] + bv, v1 = acc2[1] + bv;
    float v2 = acc2[2] + bv, v3 = acc2[3] + bv;
    float m01 = 0.5f * (v0 + v1);
    float m23 = 0.5f * (v2 + v3);
    size_t eb = (size_t)(e0 + r0) * OUTD + l15;
    out[eb] = m01;
    out[eb + OUTD] = m01;
    out[eb + 2 * OUTD] = m23;
    out[eb + 3 * OUTD] = m23;
  }
}

extern "C" void kernel_launch(void* const* d_in, const int* in_sizes, int n_in,
                              void* d_out, int out_size, void* d_ws, size_t ws_size,
                              hipStream_t stream) {
  const float* x  = (const float*)d_in[0];
  const int* eidx = (const int*)d_in[1];
  const float* W0 = (const float*)d_in[2];
  const float* b0 = (const float*)d_in[3];
  const float* W1 = (const float*)d_in[4];
  const float* b1 = (const float*)d_in[5];
  const float* W2 = (const float*)d_in[6];
  const float* b2 = (const float*)d_in[7];
  float* out = (float*)d_out;
  unsigned short* wp = (unsigned short*)d_ws;
  if (ws_size < 532480u * sizeof(unsigned short)) return;  // need ~1.04 MB scratch

  pack_weights<<<2080, 256, 0, stream>>>(W0, W1, W2, wp);
  edge_mlp<<<3125, 256, 0, stream>>>(x, eidx, b0, b1, b2, wp, out);
}

// Round 2
// 293.904 us; speedup vs baseline: 2.0954x; 2.0954x over previous
//
#include <hip/hip_runtime.h>

#define E_TOTAL 200000
#define IND 256
#define OUTD 5

typedef __attribute__((ext_vector_type(4))) float f32x4;
typedef __attribute__((ext_vector_type(16))) float f32x16;
typedef __attribute__((ext_vector_type(8))) __bf16 bf16x8;

static __device__ __forceinline__ unsigned short f2bf(float f) {
  union { float f; unsigned u; } v; v.f = f;
  unsigned u = v.u;
  unsigned r = (u + 0x7FFFu + ((u >> 16) & 1u)) >> 16;   // RNE
  return (unsigned short)r;
}

// ---------------------------------------------------------------------------
// Pack W0,W1 [512x512] into 32x32x16-bf16 B-fragment order:
//   lane l holds B[ks*16 + (l>>5)*8 + j][ntile*32 + (l&31)], j=0..7
//   off = ((ntile*32 + ks)*64 + lane)*8 + j
// W2 [512x5] padded N=16 into 16x16x32 B-fragment order (unchanged from R1):
//   lane l holds B[k0*32 + (l>>4)*8 + j][l&15]
// ws layout (ushort): [0,262144) W0p | [262144,524288) W1p | [524288,532480) W2p
// ---------------------------------------------------------------------------
__global__ __launch_bounds__(256) void pack_weights(
    const float* __restrict__ W0, const float* __restrict__ W1,
    const float* __restrict__ W2, unsigned short* __restrict__ wp) {
  int tid = blockIdx.x * 256 + threadIdx.x;
  if (tid < 2 * 262144) {
    int sel = tid >> 18;
    int t = tid & 262143;
    int n = t & 511, k = t >> 9;            // coalesced read along n
    const float* W = sel ? W1 : W0;
    float val = W[k * 512 + n];
    int ntile = n >> 5, ks = k >> 4;
    int lane = (((k >> 3) & 1) << 5) | (n & 31);
    int j = k & 7;
    int off = (((ntile * 32 + ks) * 64 + lane) << 3) | j;
    wp[sel * 262144 + off] = f2bf(val);
  } else {
    int t2 = tid - 524288;
    if (t2 < 8192) {                         // W2 padded N=5 -> 16
      int j = t2 & 7, lane = (t2 >> 3) & 63, k0 = t2 >> 9;
      int k = k0 * 32 + ((lane >> 4) << 3) + j;
      int n = lane & 15;
      float val = (n < OUTD) ? W2[k * OUTD + n] : 0.0f;
      wp[524288 + t2] = f2bf(val);
    }
  }
}

// ---------------------------------------------------------------------------
// Fused edge-MLP. One block = 64 edges, 512 threads (8 waves).
// LDS: single [64 rows][512 cols] bf16 activation buffer, XOR-swizzled
// (byte ^= (row&7)<<4) -> ds_read_b128 A-fragments and uint4 staging writes
// are both minimal (8 lanes per 4-bank slot).
// Hidden layers: wave w owns cols [w*64, w*64+64), tiles acc[m=2][nt=2] of
// mfma_f32_32x32x16_bf16, 32 k-steps with double-buffered weight prefetch
// (static phase indices; no runtime-indexed vectors -> no scratch).
// H (bias+relu, bf16) stashed in 32 packed dwords across the barrier, then
// written over A. Layer 2: waves 0..3, 16x16x32, pair-mean in-lane.
// ---------------------------------------------------------------------------
__global__ __launch_bounds__(512, 4) void edge_mlp(
    const float* __restrict__ x, const int* __restrict__ eidx,
    const float* __restrict__ b0, const float* __restrict__ b1,
    const float* __restrict__ b2, const unsigned short* __restrict__ wp,
    float* __restrict__ out) {
  __shared__ uint4 lds4[4096];               // 64 KB
  unsigned char* lds = (unsigned char*)lds4;
  const int tid = threadIdx.x;
  const int lane = tid & 63;
  const int w = tid >> 6;
  const int e0 = blockIdx.x * 64;

  // ---- stage gathered inputs: A[64][512] bf16, cols 0..255 = x[src], 256..511 = x[dst]
  {
    const int r = tid >> 3, p = tid & 7;
    const int e = e0 + r;
    const int node = (p < 4) ? eidx[e] : eidx[E_TOTAL + e];
    const float* xr = x + (size_t)node * IND + (p & 3) * 64;
    const unsigned rowb = (unsigned)r * 1024;
    const unsigned sx = (unsigned)((r & 7) << 4);
    const unsigned colb0 = (unsigned)((p < 4 ? 0 : 512) + (p & 3) * 128);
#pragma unroll
    for (int jj = 0; jj < 8; ++jj) {
      const float4 f0 = *(const float4*)(xr + jj * 8);
      const float4 f1 = *(const float4*)(xr + jj * 8 + 4);
      uint4 pk;
      pk.x = (unsigned)f2bf(f0.x) | ((unsigned)f2bf(f0.y) << 16);
      pk.y = (unsigned)f2bf(f0.z) | ((unsigned)f2bf(f0.w) << 16);
      pk.z = (unsigned)f2bf(f1.x) | ((unsigned)f2bf(f1.y) << 16);
      pk.w = (unsigned)f2bf(f1.z) | ((unsigned)f2bf(f1.w) << 16);
      *(uint4*)(lds + (rowb + ((colb0 + (unsigned)jj * 16) ^ sx))) = pk;
    }
  }
  __syncthreads();

  const int l31 = lane & 31;
  const int h = lane >> 5;
  const int l15 = lane & 15;
  const int q = lane >> 4;

#pragma unroll 1
  for (int L = 0; L < 2; ++L) {
    const unsigned short* wl = wp + L * 262144;
    const float* bias = L ? b1 : b0;

    // weight fragment base pointers for this wave's two 32-col tiles
    const unsigned short* wb0 = wl + ((size_t)((w * 2 + 0) * 2048 + lane) << 3);
    const unsigned short* wb1 = wl + ((size_t)((w * 2 + 1) * 2048 + lane) << 3);

    f32x16 acc00, acc01, acc10, acc11;
#pragma unroll
    for (int i = 0; i < 16; ++i) { acc00[i]=0.f; acc01[i]=0.f; acc10[i]=0.f; acc11[i]=0.f; }

    bf16x8 bA0 = *(const bf16x8*)(wb0);
    bf16x8 bA1 = *(const bf16x8*)(wb1);
    bf16x8 bB0, bB1;

#pragma unroll 2
    for (int ks = 0; ks < 32; ++ks) {
      const int phase = ks & 1;
      // prefetch next k-step's weights into the other buffer
      if (phase == 0) {
        if (ks < 31) { bB0 = *(const bf16x8*)(wb0 + (ks + 1) * 512); bB1 = *(const bf16x8*)(wb1 + (ks + 1) * 512); }
      } else {
        if (ks < 31) { bA0 = *(const bf16x8*)(wb0 + (ks + 1) * 512); bA1 = *(const bf16x8*)(wb1 + (ks + 1) * 512); }
      }
      bf16x8 a0, a1;
      {
        const int row0 = l31;
        const unsigned cb = (unsigned)(ks * 32 + h * 16);
        a0 = *(const bf16x8*)(lds + ((unsigned)row0 * 1024 + (cb ^ ((unsigned)(row0 & 7) << 4))));
        const int row1 = 32 + l31;
        a1 = *(const bf16x8*)(lds + ((unsigned)row1 * 1024 + (cb ^ ((unsigned)(row1 & 7) << 4))));
      }
      if (phase == 0) {
        acc00 = __builtin_amdgcn_mfma_f32_32x32x16_bf16(a0, bA0, acc00, 0, 0, 0);
        acc01 = __builtin_amdgcn_mfma_f32_32x32x16_bf16(a0, bA1, acc01, 0, 0, 0);
        acc10 = __builtin_amdgcn_mfma_f32_32x32x16_bf16(a1, bA0, acc10, 0, 0, 0);
        acc11 = __builtin_amdgcn_mfma_f32_32x32x16_bf16(a1, bA1, acc11, 0, 0, 0);
      } else {
        acc00 = __builtin_amdgcn_mfma_f32_32x32x16_bf16(a0, bB0, acc00, 0, 0, 0);
        acc01 = __builtin_amdgcn_mfma_f32_32x32x16_bf16(a0, bB1, acc01, 0, 0, 0);
        acc10 = __builtin_amdgcn_mfma_f32_32x32x16_bf16(a1, bB0, acc10, 0, 0, 0);
        acc11 = __builtin_amdgcn_mfma_f32_32x32x16_bf16(a1, bB1, acc11, 0, 0, 0);
      }
    }

    // bias + relu + pack to bf16 stash (32 dwords)
    const float bv0 = bias[w * 64 + l31];
    const float bv1 = bias[w * 64 + 32 + l31];
    unsigned sv00[8], sv01[8], sv10[8], sv11[8];
#pragma unroll
    for (int i = 0; i < 8; ++i) {
      float u0 = fmaxf(acc00[2*i] + bv0, 0.f), u1 = fmaxf(acc00[2*i+1] + bv0, 0.f);
      sv00[i] = (unsigned)f2bf(u0) | ((unsigned)f2bf(u1) << 16);
      float v0 = fmaxf(acc01[2*i] + bv1, 0.f), v1 = fmaxf(acc01[2*i+1] + bv1, 0.f);
      sv01[i] = (unsigned)f2bf(v0) | ((unsigned)f2bf(v1) << 16);
      float s0 = fmaxf(acc10[2*i] + bv0, 0.f), s1 = fmaxf(acc10[2*i+1] + bv0, 0.f);
      sv10[i] = (unsigned)f2bf(s0) | ((unsigned)f2bf(s1) << 16);
      float t0 = fmaxf(acc11[2*i] + bv1, 0.f), t1 = fmaxf(acc11[2*i+1] + bv1, 0.f);
      sv11[i] = (unsigned)f2bf(t0) | ((unsigned)f2bf(t1) << 16);
    }
    __syncthreads();   // all waves done reading A

    // write H over A.  C layout: col = lane&31, row = (reg&3)+8*(reg>>2)+4*h
    {
      const unsigned cb0 = (unsigned)(w * 64 + l31) * 2;
      const unsigned cb1 = (unsigned)(w * 64 + 32 + l31) * 2;
#pragma unroll
      for (int i = 0; i < 8; ++i) {
        const int reg0 = 2 * i, reg1 = 2 * i + 1;
        const int ra = (reg0 & 3) + 8 * (reg0 >> 2) + 4 * h;
        const int rb = (reg1 & 3) + 8 * (reg1 >> 2) + 4 * h;
        const int ra1 = 32 + ra, rb1 = 32 + rb;
        *(unsigned short*)(lds + ((unsigned)ra * 1024 + (cb0 ^ ((unsigned)(ra & 7) << 4)))) = (unsigned short)(sv00[i] & 0xffff);
        *(unsigned short*)(lds + ((unsigned)rb * 1024 + (cb0 ^ ((unsigned)(rb & 7) << 4)))) = (unsigned short)(sv00[i] >> 16);
        *(unsigned short*)(lds + ((unsigned)ra * 1024 + (cb1 ^ ((unsigned)(ra & 7) << 4)))) = (unsigned short)(sv01[i] & 0xffff);
        *(unsigned short*)(lds + ((unsigned)rb * 1024 + (cb1 ^ ((unsigned)(rb & 7) << 4)))) = (unsigned short)(sv01[i] >> 16);
        *(unsigned short*)(lds + ((unsigned)ra1 * 1024 + (cb0 ^ ((unsigned)(ra1 & 7) << 4)))) = (unsigned short)(sv10[i] & 0xffff);
        *(unsigned short*)(lds + ((unsigned)rb1 * 1024 + (cb0 ^ ((unsigned)(rb1 & 7) << 4)))) = (unsigned short)(sv10[i] >> 16);
        *(unsigned short*)(lds + ((unsigned)ra1 * 1024 + (cb1 ^ ((unsigned)(ra1 & 7) << 4)))) = (unsigned short)(sv11[i] & 0xffff);
        *(unsigned short*)(lds + ((unsigned)rb1 * 1024 + (cb1 ^ ((unsigned)(rb1 & 7) << 4)))) = (unsigned short)(sv11[i] >> 16);
      }
    }
    __syncthreads();
  }

  // output layer: waves 0..3, wave w -> rows w*16..w*16+15 (16x16x32), N=16 padded
  if (w < 4) {
    f32x4 acc2; acc2[0]=0.f; acc2[1]=0.f; acc2[2]=0.f; acc2[3]=0.f;
    for (int k0 = 0; k0 < 16; ++k0) {
      const int row = w * 16 + l15;
      unsigned boff = (unsigned)row * 1024 +
                      (((unsigned)(k0 * 64 + q * 16)) ^ ((unsigned)(row & 7) << 4));
      bf16x8 a = *(const bf16x8*)(lds + boff);
      const unsigned short* bp = wp + 524288 + ((size_t)(k0 * 64 + lane) << 3);
      bf16x8 b = *(const bf16x8*)bp;
      acc2 = __builtin_amdgcn_mfma_f32_16x16x32_bf16(a, b, acc2, 0, 0, 0);
    }
    if (l15 < OUTD) {
      const float bv = b2[l15];
      const int r0 = w * 16 + q * 4;          // block-local edge row (even)
      float v0 = acc2[0] + bv, v1 = acc2[1] + bv;
      float v2 = acc2[2] + bv, v3 = acc2[3] + bv;
      float m01 = 0.5f * (v0 + v1);
      float m23 = 0.5f * (v2 + v3);
      size_t eb = (size_t)(e0 + r0) * OUTD + l15;
      out[eb] = m01;
      out[eb + OUTD] = m01;
      out[eb + 2 * OUTD] = m23;
      out[eb + 3 * OUTD] = m23;
    }
  }
}

extern "C" void kernel_launch(void* const* d_in, const int* in_sizes, int n_in,
                              void* d_out, int out_size, void* d_ws, size_t ws_size,
                              hipStream_t stream) {
  const float* x  = (const float*)d_in[0];
  const int* eidx = (const int*)d_in[1];
  const float* W0 = (const float*)d_in[2];
  const float* b0 = (const float*)d_in[3];
  const float* W1 = (const float*)d_in[4];
  const float* b1 = (const float*)d_in[5];
  const float* W2 = (const float*)d_in[6];
  const float* b2 = (const float*)d_in[7];
  float* out = (float*)d_out;
  unsigned short* wp = (unsigned short*)d_ws;
  if (ws_size < 532480u * sizeof(unsigned short)) return;  // ~1.04 MB scratch

  pack_weights<<<2080, 256, 0, stream>>>(W0, W1, W2, wp);
  edge_mlp<<<3125, 512, 0, stream>>>(x, eidx, b0, b1, b2, wp, out);
}